// Round 1
// baseline (1361.366 us; speedup 1.0000x reference)
//
#include <hip/hip_runtime.h>
#include <hip/hip_bf16.h>

// ---------------------------------------------------------------------------
// SeqdistModel (bonito CTC-CRF): conv(stride5)+tanh -> linear -> 5*tanh scores
// -> log-semiring forward (logZ) -> out = scores - logZ/T
// Shapes: x[32,1,4000], conv_w[320,1,19], conv_b[320], lin_w[320,5120],
//         lin_b[5120]; out [800,32,5120] fp32.
// ---------------------------------------------------------------------------

typedef __attribute__((ext_vector_type(8))) short bf16x8;
typedef __attribute__((ext_vector_type(4))) float f32x4;

#define T_STEPS 800
#define NBATCH 32
#define FEAT 320
#define CNZ 5120
#define MROWS (T_STEPS * NBATCH)   // 25600

__device__ __forceinline__ float fast_tanh(float x) {
    // tanh(x) = 1 - 2/(e^{2x}+1);  e^{2x} = 2^{x * 2*log2(e)}
    float e = exp2f(x * 2.8853900817779268f);
    return 1.0f - 2.0f * __builtin_amdgcn_rcpf(e + 1.0f);
}

// ---- 1. conv (stride 5, SAME: pad 7/7) + tanh -> bf16 y[25600,320] ---------
__global__ __launch_bounds__(320) void conv_kernel(
    const float* __restrict__ x, const float* __restrict__ w,
    const float* __restrict__ b, __hip_bfloat16* __restrict__ y) {
    int m = blockIdx.x;            // m = t*32 + n
    int t = m >> 5, n = m & 31;
    int f = threadIdx.x;
    __shared__ float xs[19];
    int base = t * 5 - 7;
    if (f < 19) {
        int pos = base + f;
        xs[f] = (pos >= 0 && pos < 4000) ? x[n * 4000 + pos] : 0.0f;
    }
    __syncthreads();
    float acc = b[f];
#pragma unroll
    for (int k = 0; k < 19; ++k) acc = fmaf(xs[k], w[f * 19 + k], acc);
    y[(size_t)m * FEAT + f] = __float2bfloat16(fast_tanh(acc));
}

// ---- 2. transpose lin_w [320,5120] fp32 -> Wt [5120,320] bf16 --------------
__global__ __launch_bounds__(256) void transpose_w(
    const float* __restrict__ W, __hip_bfloat16* __restrict__ Wt) {
    __shared__ float tile[64][65];
    int nb = blockIdx.x * 64, kb = blockIdx.y * 64;
    int tx = threadIdx.x & 63, ty = threadIdx.x >> 6;   // 64 x 4
#pragma unroll
    for (int r = 0; r < 64; r += 4)
        tile[ty + r][tx] = W[(size_t)(kb + ty + r) * CNZ + nb + tx];
    __syncthreads();
#pragma unroll
    for (int r = 0; r < 64; r += 4) {
        int nn = ty + r;
        Wt[(size_t)(nb + nn) * FEAT + kb + tx] = __float2bfloat16(tile[tx][nn]);
    }
}

// ---- 3. GEMM: scores[m,n] = 5*tanh(sum_k A[m,k]*Wt[n,k] + bias[n]) ---------
#define GBM 128
#define GBN 128
#define GBK 64
#define LDK 72   // 64 + 8 shorts pad (keeps 16B alignment, breaks bank stride)

__global__ __launch_bounds__(256) void gemm_kernel(
    const __hip_bfloat16* __restrict__ A,    // [25600,320] bf16
    const __hip_bfloat16* __restrict__ Bt,   // [5120,320]  bf16
    const float* __restrict__ bias,          // [5120]
    float* __restrict__ out) {               // [25600,5120] fp32
    __shared__ __align__(16) short As[GBM * LDK];
    __shared__ __align__(16) short Bs[GBN * LDK];
    const int K = FEAT;
    int bm0 = blockIdx.x * GBM;
    int bn0 = blockIdx.y * GBN;
    int tid = threadIdx.x;
    int wave = tid >> 6, lane = tid & 63;
    int wm = (wave >> 1) * 64, wn = (wave & 1) * 64;
    int col = lane & 15, quad = lane >> 4;

    f32x4 acc[4][4];
#pragma unroll
    for (int i = 0; i < 4; ++i)
#pragma unroll
        for (int j = 0; j < 4; ++j) acc[i][j] = (f32x4){0.f, 0.f, 0.f, 0.f};

    for (int k0 = 0; k0 < K; k0 += GBK) {
#pragma unroll
        for (int p = 0; p < 4; ++p) {
            int i = p * 256 + tid;
            int row = i >> 3, cg = i & 7;
            *(int4*)&As[row * LDK + cg * 8] =
                *(const int4*)&A[(size_t)(bm0 + row) * K + k0 + cg * 8];
            *(int4*)&Bs[row * LDK + cg * 8] =
                *(const int4*)&Bt[(size_t)(bn0 + row) * K + k0 + cg * 8];
        }
        __syncthreads();
#pragma unroll
        for (int kk = 0; kk < GBK; kk += 32) {
            bf16x8 af[4], bfr[4];
#pragma unroll
            for (int i = 0; i < 4; ++i)
                af[i] = *(bf16x8*)&As[(wm + i * 16 + col) * LDK + kk + quad * 8];
#pragma unroll
            for (int j = 0; j < 4; ++j)
                bfr[j] = *(bf16x8*)&Bs[(wn + j * 16 + col) * LDK + kk + quad * 8];
#pragma unroll
            for (int i = 0; i < 4; ++i)
#pragma unroll
                for (int j = 0; j < 4; ++j)
                    acc[i][j] = __builtin_amdgcn_mfma_f32_16x16x32_bf16(
                        af[i], bfr[j], acc[i][j], 0, 0, 0);
        }
        __syncthreads();
    }
    // epilogue: D row = quad*4+r (M), col = lane&15 (N)
#pragma unroll
    for (int j = 0; j < 4; ++j) {
        int n_g = bn0 + wn + j * 16 + col;
        float bj = bias[n_g];
#pragma unroll
        for (int i = 0; i < 4; ++i) {
            int m_base = bm0 + wm + i * 16 + quad * 4;
#pragma unroll
            for (int r = 0; r < 4; ++r) {
                out[(size_t)(m_base + r) * CNZ + n_g] =
                    5.0f * fast_tanh(acc[i][j][r] + bj);
            }
        }
    }
}

// ---- 4. forward algorithm (log-semiring), one block per batch element ------
// idx[c] = {c, c>>2, (c>>2)+256, (c>>2)+512, (c>>2)+768}
__global__ __launch_bounds__(1024) void forward_kernel(
    const float* __restrict__ scores, float* __restrict__ corr) {
    __shared__ float A0[1024];
    __shared__ float A1[1024];
    const int c = threadIdx.x;
    const int n = blockIdx.x;
    const int q = c >> 2;
    const float L2E = 1.4426950408889634f;
    const float LN2 = 0.6931471805599453f;
    A0[c] = 0.0f;
    __syncthreads();
    const size_t tstride = (size_t)NBATCH * CNZ;
    const float* p = scores + (size_t)n * CNZ + c * 5;
    float s0 = p[0], s1 = p[1], s2 = p[2], s3 = p[3], s4 = p[4];
    for (int t = 0; t < T_STEPS; ++t) {
        const float* pn = p + tstride;
        float u0 = 0.f, u1 = 0.f, u2 = 0.f, u3 = 0.f, u4 = 0.f;
        if (t < T_STEPS - 1) { u0 = pn[0]; u1 = pn[1]; u2 = pn[2]; u3 = pn[3]; u4 = pn[4]; }
        float* cur = (t & 1) ? A1 : A0;
        float* nxt = (t & 1) ? A0 : A1;
        float x0 = s0 + cur[c];
        float x1 = s1 + cur[q];
        float x2 = s2 + cur[q + 256];
        float x3 = s3 + cur[q + 512];
        float x4 = s4 + cur[q + 768];
        float mx = fmaxf(fmaxf(fmaxf(x0, x1), fmaxf(x2, x3)), x4);
        float sum = exp2f((x0 - mx) * L2E) + exp2f((x1 - mx) * L2E) +
                    exp2f((x2 - mx) * L2E) + exp2f((x3 - mx) * L2E) +
                    exp2f((x4 - mx) * L2E);
        nxt[c] = fmaf(log2f(sum), LN2, mx);
        __syncthreads();
        p = pn; s0 = u0; s1 = u1; s2 = u2; s3 = u3; s4 = u4;
    }
    // final alpha lives in A0 (last step t=799 odd -> nxt==A0)
    float v = A0[c];
    A1[c] = v;
    __syncthreads();
    for (int s = 512; s > 0; s >>= 1) {
        if (c < s) A1[c] = fmaxf(A1[c], A1[c + s]);
        __syncthreads();
    }
    float mx = A1[0];
    __syncthreads();
    A1[c] = exp2f((v - mx) * L2E);
    __syncthreads();
    for (int s = 512; s > 0; s >>= 1) {
        if (c < s) A1[c] += A1[c + s];
        __syncthreads();
    }
    if (c == 0)
        corr[n] = fmaf(log2f(A1[0]), LN2, mx) * (1.0f / (float)T_STEPS);
}

// ---- 5. out -= corr[n]  (float4, n = (i4/1280) & 31) -----------------------
__global__ __launch_bounds__(256) void sub_kernel(
    float* __restrict__ out, const float* __restrict__ corr) {
    size_t i4 = (size_t)blockIdx.x * blockDim.x + threadIdx.x;
    float cc = corr[(i4 / (CNZ / 4)) & (NBATCH - 1)];
    float4* o4 = (float4*)out;
    float4 v = o4[i4];
    v.x -= cc; v.y -= cc; v.z -= cc; v.w -= cc;
    o4[i4] = v;
}

extern "C" void kernel_launch(void* const* d_in, const int* in_sizes, int n_in,
                              void* d_out, int out_size, void* d_ws, size_t ws_size,
                              hipStream_t stream) {
    const float* x      = (const float*)d_in[0];
    const float* conv_w = (const float*)d_in[1];
    const float* conv_b = (const float*)d_in[2];
    const float* lin_w  = (const float*)d_in[3];
    const float* lin_b  = (const float*)d_in[4];
    float* out = (float*)d_out;

    char* ws = (char*)d_ws;
    __hip_bfloat16* y  = (__hip_bfloat16*)ws;                       // 16,384,000 B
    __hip_bfloat16* wt = (__hip_bfloat16*)(ws + 16384000);          //  3,276,800 B
    float* corr        = (float*)(ws + 16384000 + 3276800);         //        128 B

    conv_kernel<<<MROWS, 320, 0, stream>>>(x, conv_w, conv_b, y);
    transpose_w<<<dim3(CNZ / 64, FEAT / 64), 256, 0, stream>>>(lin_w, wt);
    gemm_kernel<<<dim3(MROWS / GBM, CNZ / GBN), 256, 0, stream>>>(y, wt, lin_b, out);
    forward_kernel<<<NBATCH, 1024, 0, stream>>>(out, corr);
    sub_kernel<<<(out_size / 4) / 256, 256, 0, stream>>>(out, corr);
}